// Round 12
// baseline (99.648 us; speedup 1.0000x reference)
//
#include <hip/hip_runtime.h>

constexpr int NPTS  = 1024;   // points per batch
constexpr int NT    = 21;     // targets per batch
constexpr int KSEL  = 64;     // top-k
constexpr int PPL   = 16;     // points per lane (1024 / 64)
constexpr int NXCD  = 8;
constexpr int BLOCK = 512;    // 8 waves: 4 producers + 4 consumers
constexpr int RPB   = 3;      // production rounds per block
constexpr int BTPB  = 4 * RPB;// 12 bt per block -> 896 blocks (div by 8)

typedef float f32x4 __attribute__((ext_vector_type(4)));

__device__ __forceinline__ unsigned key_of(float d) {
    // monotone float->uint transform (total order matching float <)
    unsigned u = __float_as_uint(d);
    return (u & 0x80000000u) ? ~u : (u | 0x80000000u);
}

__device__ __forceinline__ unsigned mbcnt64(unsigned long long m) {
    unsigned lo = __builtin_amdgcn_mbcnt_lo((unsigned)m, 0u);
    return __builtin_amdgcn_mbcnt_hi((unsigned)(m >> 32), lo);
}

__global__ __launch_bounds__(BLOCK) void knn_prodcons_kernel(
    const float* __restrict__ pc,   // (B, 1024, 3)
    const float* __restrict__ tgt,  // (B, 21, 3)
    float* __restrict__ out,        // (B, 21, 1024, 3)
    int total_bt)
{
    const int wid  = threadIdx.x >> 6;   // 0..7
    const int lane = threadIdx.x & 63;

    // bijective XCD swizzle (gridDim.x divisible by 8)
    int sbid = blockIdx.x;
    if ((gridDim.x & (NXCD - 1)) == 0) {
        const int cpx = gridDim.x / NXCD;
        sbid = ((int)blockIdx.x % NXCD) * cpx + (int)blockIdx.x / NXCD;
    }
    const int bt0 = sbid * BTPB;

    // double-buffered per-bt blend words: cb0 (12 bits) | cb1 (12 bits) << 12
    __shared__ unsigned cbuf[2][4][64];

    const bool producer = (wid < 4);     // wave-uniform role split

    for (int r = 0; r <= RPB; ++r) {
        if (producer && r < RPB) {
            // ---------------- PRODUCER: select for bt, emit blend words ----
            const int bt = bt0 + r * 4 + wid;
            if (bt < total_bt) {
                const int b  = bt / NT;
                const int tq = bt % NT;
                const float* base = pc + (size_t)b * (NPTS * 3);
                const float* tp   = tgt + ((size_t)b * NT + tq) * 3;
                const float  t0 = tp[0], t1 = tp[1], t2 = tp[2];
                const float  dt = t0 * t0 + t1 * t1 + t2 * t2;

                // keys: strided ownership, same fp expression as r5-r8
                unsigned key[PPL];
                #pragma unroll
                for (int i = 0; i < PPL; ++i) {
                    const float* pp = base + 3 * (64 * i + lane);
                    const float p0 = pp[0], p1 = pp[1], p2 = pp[2];
                    const float d  = dt + (p0 * p0 + p1 * p1 + p2 * p2)
                                        - 2.0f * (t0 * p0 + t1 * p1 + t2 * p2);
                    key[i] = key_of(d);
                }

                // threshold-form exact select of the KSEL-th smallest (r8)
                unsigned kand = key[0], kor = key[0];
                #pragma unroll
                for (int i = 1; i < PPL; ++i) { kand &= key[i]; kor |= key[i]; }
                #pragma unroll
                for (int off = 32; off > 0; off >>= 1) {
                    kand &= (unsigned)__shfl_xor((int)kand, off, 64);
                    kor  |= (unsigned)__shfl_xor((int)kor,  off, 64);
                }
                const unsigned dis = kor & ~kand;

                unsigned lo = 0, below = 0, want = KSEL, cls = NPTS;
                bool     early = false;
                unsigned Tsel = 0, kth = 0;
                if (dis == 0u) {
                    kth = kand;
                } else {
                    const int hb = 31 - __builtin_clz(dis);
                    lo = (hb == 31) ? 0u : (kand & (~0u << (hb + 1)));
                    for (int s = hb; s >= 0; --s) {
                        const unsigned mid = lo | (1u << s);
                        unsigned cnt = 0;
                        #pragma unroll
                        for (int i = 0; i < PPL; ++i) cnt += (key[i] < mid) ? 1u : 0u;
                        unsigned c = 0;
                        #pragma unroll
                        for (int j = 0; j < 5; ++j)
                            c += (unsigned)__popcll(__ballot((cnt >> j) & 1u)) << j;
                        const unsigned t = c - below;   // size of class-0 = [lo, mid)
                        if (want <= t) { cls = t; }
                        else { want -= t; below = c; lo = mid; cls -= t; }
                        if (cls == want) { early = true; Tsel = lo + (1u << s); break; }
                    }
                    if (!early) kth = lo;
                }

                // selection flags: bit i => point (64*i + lane)
                unsigned selmask = 0;
                if (early) {
                    #pragma unroll
                    for (int i = 0; i < PPL; ++i)
                        if (key[i] < Tsel) selmask |= (1u << i);
                } else {
                    unsigned run_tot = 0;   // stable lowest-index tie-break
                    #pragma unroll
                    for (int i = 0; i < PPL; ++i) {
                        const bool eq = (key[i] == kth);
                        const unsigned long long bal = __ballot(eq);
                        const bool sel_eq = eq && (run_tot + mbcnt64(bal)) < want;
                        if (key[i] < kth || sel_eq) selmask |= (1u << i);
                        run_tot += (unsigned)__popcll(bal);
                    }
                }

                // blend words for store-lane `lane` (r5/r10 verified mapping):
                // chunk m = 64*j + lane covers points q = 4m/3 and q+1;
                // point p's bit = bit (p>>6) of selmask entry (p&63).
                unsigned cb0 = 0, cb1 = 0;
                #pragma unroll
                for (int j = 0; j < 12; ++j) {
                    const int      m  = 64 * j + lane;
                    const unsigned e0 = 4u * (unsigned)m;
                    const unsigned q  = e0 / 3u;
                    const unsigned q1 = q + 1u;
                    const unsigned sm0 = (unsigned)__shfl((int)selmask, (int)(q  & 63u), 64);
                    const unsigned sm1 = (unsigned)__shfl((int)selmask, (int)(q1 & 63u), 64);
                    cb0 |= ((sm0 >> (q  >> 6)) & 1u) << j;
                    cb1 |= ((sm1 >> (q1 >> 6)) & 1u) << j;
                }
                cbuf[r & 1][wid][lane] = cb0 | (cb1 << 12);
            }
        }
        if (!producer && r >= 1) {
            // ---------------- CONSUMER: pure streaming masked store --------
            const int bt = bt0 + (r - 1) * 4 + (wid - 4);
            if (bt < total_bt) {
                const int b = bt / NT;
                const f32x4* src4 = reinterpret_cast<const f32x4*>(pc + (size_t)b * (NPTS * 3));
                f32x4*       dst4 = reinterpret_cast<f32x4*>(out + (size_t)bt * (NPTS * 3));
                const unsigned cw  = cbuf[(r - 1) & 1][wid - 4][lane];
                const unsigned cb0 = cw & 0xFFFu;
                const unsigned cb1 = cw >> 12;
                #pragma unroll
                for (int j = 0; j < 12; ++j) {
                    const int      m  = 64 * j + lane;
                    const f32x4    g  = src4[m];        // L1/L2-hot row
                    const unsigned e0 = 4u * (unsigned)m;
                    const unsigned q  = e0 / 3u;
                    const unsigned u  = e0 - 3u * q;    // 0..2
                    const unsigned b0 = (cb0 >> j) & 1u;
                    const unsigned b1 = (cb1 >> j) & 1u;
                    f32x4 v;
                    v.x = b0                    ? g.x : 0.0f;  // elem e0   -> point q
                    v.y = ((u == 2u) ? b1 : b0) ? g.y : 0.0f;  // elem e0+1
                    v.z = ((u == 0u) ? b0 : b1) ? g.z : 0.0f;  // elem e0+2
                    v.w = b1                    ? g.w : 0.0f;  // elem e0+3 -> point q+1
                    dst4[m] = v;
                }
            }
        }
        __syncthreads();   // all 8 waves, every round (wave-uniform control flow)
    }
}

extern "C" void kernel_launch(void* const* d_in, const int* in_sizes, int n_in,
                              void* d_out, int out_size, void* d_ws, size_t ws_size,
                              hipStream_t stream) {
    const float* pc  = (const float*)d_in[0];  // (B,1024,3)
    const float* tgt = (const float*)d_in[1];  // (B,21,3)
    float*       out = (float*)d_out;          // (B,21,1024,3)

    const int B        = in_sizes[0] / (NPTS * 3);        // 512
    const int total_bt = B * NT;                           // 10752
    const int nblocks  = (total_bt + BTPB - 1) / BTPB;     // 896 (divisible by 8)

    knn_prodcons_kernel<<<nblocks, BLOCK, 0, stream>>>(pc, tgt, out, total_bt);
}

// Round 13
// 50.480 us; speedup vs baseline: 1.9740x; 1.9740x over previous
//
#include <hip/hip_runtime.h>

constexpr int NPTS  = 1024;   // points per batch
constexpr int NT    = 21;     // targets per batch
constexpr int KSEL  = 64;     // top-k
constexpr int BLOCK = 256;    // 4 waves, 1 wave per (b,t)
constexpr int PPL   = 16;     // points per lane (1024 / 64)
constexpr int NXCD  = 8;

// Occupancy throttle: 64 KB dynamic LDS -> 2 blocks/CU (160 KB pool).
// Keeps the in-flight zero-written output footprint per XCD (~3.1 MB)
// inside the 4 MiB XCD L2 so value stores merge into still-dirty lines.
constexpr size_t LDS_THROTTLE = 64 * 1024;

typedef float f32x4 __attribute__((ext_vector_type(4)));

__device__ __forceinline__ unsigned key_of(float d) {
    // monotone float->uint transform (total order matching float <)
    unsigned u = __float_as_uint(d);
    return (u & 0x80000000u) ? ~u : (u | 0x80000000u);
}

__device__ __forceinline__ unsigned mbcnt64(unsigned long long m) {
    unsigned lo = __builtin_amdgcn_mbcnt_lo((unsigned)m, 0u);
    return __builtin_amdgcn_mbcnt_hi((unsigned)(m >> 32), lo);
}

__global__ __launch_bounds__(BLOCK) void knn_mask_throttled_kernel(
    const float* __restrict__ pc,   // (B, 1024, 3)
    const float* __restrict__ tgt,  // (B, 21, 3)
    float* __restrict__ out,        // (B, 21, 1024, 3)
    int total_bt)
{
    extern __shared__ char _pad[];       // occupancy throttle (allocated, unused)

    const int wave = threadIdx.x >> 6;
    const int lane = threadIdx.x & 63;
    // bijective XCD swizzle (gridDim.x divisible by 8)
    const int cpx  = gridDim.x / NXCD;
    const int sbid = ((int)blockIdx.x % NXCD) * cpx + (int)blockIdx.x / NXCD;
    const int bt   = sbid * 4 + wave;
    if (bt >= total_bt) return;          // wave-uniform
    if (total_bt < 0) _pad[0] = (char)lane;   // never true; keeps _pad alive
    const int b  = bt / NT;
    const int tq = bt % NT;

    const float* base  = pc  + (size_t)b  * (NPTS * 3);
    float*       obase = out + (size_t)bt * (NPTS * 3);

    // ---- phase 0: select-independent zeroing of the whole output row ----
    {
        f32x4* dst4 = reinterpret_cast<f32x4*>(obase);
        const f32x4 z = {0.0f, 0.0f, 0.0f, 0.0f};
        #pragma unroll
        for (int j = 0; j < 12; ++j) dst4[64 * j + lane] = z;
    }

    // target point (wave-uniform, L1-broadcast)
    const float* tp = tgt + ((size_t)b * NT + tq) * 3;
    const float  t0 = tp[0], t1 = tp[1], t2 = tp[2];
    const float  dt = t0 * t0 + t1 * t1 + t2 * t2;

    // ---- phase 1: strided ownership (lane owns points 64*i + lane) ----
    unsigned key[PPL];
    #pragma unroll
    for (int i = 0; i < PPL; ++i) {
        const float* pp = base + 3 * (64 * i + lane);
        const float p0 = pp[0], p1 = pp[1], p2 = pp[2];
        const float d  = dt + (p0 * p0 + p1 * p1 + p2 * p2)
                            - 2.0f * (t0 * p0 + t1 * p1 + t2 * p2);
        key[i] = key_of(d);
    }

    // ---- phase 2: threshold-form exact select of the KSEL-th smallest ----
    unsigned kand = key[0], kor = key[0];
    #pragma unroll
    for (int i = 1; i < PPL; ++i) { kand &= key[i]; kor |= key[i]; }
    #pragma unroll
    for (int off = 32; off > 0; off >>= 1) {
        kand &= (unsigned)__shfl_xor((int)kand, off, 64);
        kor  |= (unsigned)__shfl_xor((int)kor,  off, 64);
    }
    const unsigned dis = kor & ~kand;    // bits where keys disagree

    unsigned lo = 0, below = 0, want = KSEL, cls = NPTS;
    bool     early = false;
    unsigned Tsel = 0, kth = 0;
    if (dis == 0u) {
        kth = kand;                       // all 1024 keys identical
    } else {
        const int hb = 31 - __builtin_clz(dis);
        lo = (hb == 31) ? 0u : (kand & (~0u << (hb + 1)));  // common high bits
        for (int s = hb; s >= 0; --s) {
            const unsigned mid = lo | (1u << s);
            unsigned cnt = 0;
            #pragma unroll
            for (int i = 0; i < PPL; ++i) cnt += (key[i] < mid) ? 1u : 0u;
            unsigned c = 0;               // wave total via 5-ballot decompose
            #pragma unroll
            for (int j = 0; j < 5; ++j)
                c += (unsigned)__popcll(__ballot((cnt >> j) & 1u)) << j;
            const unsigned t = c - below; // size of class-0 = [lo, mid)
            if (want <= t) { cls = t; }
            else { want -= t; below = c; lo = mid; cls -= t; }
            if (cls == want) { early = true; Tsel = lo + (1u << s); break; }
        }
        if (!early) kth = lo;
    }

    // ---- phase 3: selection flags. bit i => point (64*i + lane). ----
    unsigned selmask = 0;
    if (early) {
        #pragma unroll
        for (int i = 0; i < PPL; ++i)
            if (key[i] < Tsel) selmask |= (1u << i);
    } else {
        unsigned run_tot = 0;   // stable lowest-index ties: index = 64*i + lane
        #pragma unroll
        for (int i = 0; i < PPL; ++i) {
            const bool eq = (key[i] == kth);
            const unsigned long long bal = __ballot(eq);
            const bool sel_eq = eq && (run_tot + mbcnt64(bal)) < want;
            if (key[i] < kth || sel_eq) selmask |= (1u << i);
            run_tot += (unsigned)__popcll(bal);
        }
    }

    // ---- phase 4: store ONLY the selected points (~1/lane, 12 B each).
    // vmcnt(0) orders vs the phase-0 zero stores (retired long ago); with the
    // occupancy throttle the zero lines are still dirty in this XCD's L2 ->
    // value stores merge; HBM writes stay ~129 MB.
    asm volatile("s_waitcnt vmcnt(0)" ::: "memory");
    unsigned sm = selmask;
    while (sm) {
        const int i = __builtin_ctz(sm);
        sm &= sm - 1u;
        const int q = 64 * i + lane;
        const float* pp = base  + 3 * q;   // L1/L2-hot (read in phase 1)
        float*       op = obase + 3 * q;
        op[0] = pp[0];
        op[1] = pp[1];
        op[2] = pp[2];
    }
}

extern "C" void kernel_launch(void* const* d_in, const int* in_sizes, int n_in,
                              void* d_out, int out_size, void* d_ws, size_t ws_size,
                              hipStream_t stream) {
    const float* pc  = (const float*)d_in[0];  // (B,1024,3)
    const float* tgt = (const float*)d_in[1];  // (B,21,3)
    float*       out = (float*)d_out;          // (B,21,1024,3)

    const int B        = in_sizes[0] / (NPTS * 3);   // 512
    const int total_bt = B * NT;                      // 10752
    const int nblocks  = (total_bt + 3) / 4;          // 2688 (divisible by 8)

    knn_mask_throttled_kernel<<<nblocks, BLOCK, LDS_THROTTLE, stream>>>(
        pc, tgt, out, total_bt);
}

// Round 14
// 40.426 us; speedup vs baseline: 2.4649x; 1.2487x over previous
//
#include <hip/hip_runtime.h>

constexpr int NPTS  = 1024;   // points per batch
constexpr int NT    = 21;     // targets per batch
constexpr int KSEL  = 64;     // top-k
constexpr int BLOCK = 256;    // 4 waves, 1 wave per (b,t)
constexpr int PPL   = 16;     // points per lane (1024 / 64)
constexpr int NXCD  = 8;

typedef float f32x4 __attribute__((ext_vector_type(4)));

__device__ __forceinline__ unsigned key_of(float d) {
    // monotone float->uint transform (total order matching float <)
    unsigned u = __float_as_uint(d);
    return (u & 0x80000000u) ? ~u : (u | 0x80000000u);
}

__device__ __forceinline__ unsigned mbcnt64(unsigned long long m) {
    unsigned lo = __builtin_amdgcn_mbcnt_lo((unsigned)m, 0u);
    return __builtin_amdgcn_mbcnt_hi((unsigned)(m >> 32), lo);
}

__global__ __launch_bounds__(BLOCK) void knn_mask_burst_kernel(
    const float* __restrict__ pc,   // (B, 1024, 3)
    const float* __restrict__ tgt,  // (B, 21, 3)
    float* __restrict__ out,        // (B, 21, 1024, 3)
    int total_bt)
{
    const int wave = threadIdx.x >> 6;
    const int lane = threadIdx.x & 63;
    // bijective XCD swizzle (gridDim.x divisible by 8)
    const int cpx  = gridDim.x / NXCD;
    const int sbid = ((int)blockIdx.x % NXCD) * cpx + (int)blockIdx.x / NXCD;
    const int bt   = sbid * 4 + wave;
    if (bt >= total_bt) return;          // wave-uniform
    const int b  = bt / NT;
    const int tq = bt % NT;

    const float* base = pc + (size_t)b * (NPTS * 3);
    const f32x4* src4 = reinterpret_cast<const f32x4*>(base);

    // target point (wave-uniform, L1-broadcast)
    const float* tp = tgt + ((size_t)b * NT + tq) * 3;
    const float  t0 = tp[0], t1 = tp[1], t2 = tp[2];
    const float  dt = t0 * t0 + t1 * t1 + t2 * t2;

    // ---- phase 1: keys, strided ownership (lane owns points 64*i + lane) ----
    unsigned key[PPL];
    #pragma unroll
    for (int i = 0; i < PPL; ++i) {
        const float* pp = base + 3 * (64 * i + lane);
        const float p0 = pp[0], p1 = pp[1], p2 = pp[2];
        const float d  = dt + (p0 * p0 + p1 * p1 + p2 * p2)
                            - 2.0f * (t0 * p0 + t1 * p1 + t2 * p2);
        key[i] = key_of(d);
    }

    // ---- phase 1b: ISSUE all 12 chunk loads for the store phase NOW.
    // They retire for free under the ~2.6k-cycle select chain, so the store
    // phase becomes a pure 12-store burst with no per-chunk vmcnt dribble.
    f32x4 g[12];
    #pragma unroll
    for (int j = 0; j < 12; ++j) g[j] = src4[64 * j + lane];

    // ---- phase 2: threshold-form exact select of the KSEL-th smallest (r8) ----
    unsigned kand = key[0], kor = key[0];
    #pragma unroll
    for (int i = 1; i < PPL; ++i) { kand &= key[i]; kor |= key[i]; }
    #pragma unroll
    for (int off = 32; off > 0; off >>= 1) {
        kand &= (unsigned)__shfl_xor((int)kand, off, 64);
        kor  |= (unsigned)__shfl_xor((int)kor,  off, 64);
    }
    const unsigned dis = kor & ~kand;    // bits where keys disagree

    unsigned lo = 0, below = 0, want = KSEL, cls = NPTS;
    bool     early = false;
    unsigned Tsel = 0, kth = 0;
    if (dis == 0u) {
        kth = kand;                       // all 1024 keys identical
    } else {
        const int hb = 31 - __builtin_clz(dis);
        lo = (hb == 31) ? 0u : (kand & (~0u << (hb + 1)));  // common high bits
        for (int s = hb; s >= 0; --s) {
            const unsigned mid = lo | (1u << s);
            unsigned cnt = 0;
            #pragma unroll
            for (int i = 0; i < PPL; ++i) cnt += (key[i] < mid) ? 1u : 0u;
            unsigned c = 0;               // wave total via 5-ballot decompose
            #pragma unroll
            for (int j = 0; j < 5; ++j)
                c += (unsigned)__popcll(__ballot((cnt >> j) & 1u)) << j;
            const unsigned t = c - below; // size of class-0 = [lo, mid)
            if (want <= t) { cls = t; }
            else { want -= t; below = c; lo = mid; cls -= t; }
            if (cls == want) { early = true; Tsel = lo + (1u << s); break; }
        }
        if (!early) kth = lo;
    }

    // ---- phase 3: selection flags. bit i => point (64*i + lane). ----
    unsigned selmask = 0;
    if (early) {
        #pragma unroll
        for (int i = 0; i < PPL; ++i)
            if (key[i] < Tsel) selmask |= (1u << i);
    } else {
        unsigned run_tot = 0;   // stable lowest-index ties: index = 64*i + lane
        #pragma unroll
        for (int i = 0; i < PPL; ++i) {
            const bool eq = (key[i] == kth);
            const unsigned long long bal = __ballot(eq);
            const bool sel_eq = eq && (run_tot + mbcnt64(bal)) < want;
            if (key[i] < kth || sel_eq) selmask |= (1u << i);
            run_tot += (unsigned)__popcll(bal);
        }
    }

    // ---- phase 3b: per-chunk blend bits via bpermute (VALU/LDS only) ----
    unsigned cb0 = 0, cb1 = 0;   // bit j: select bit for point q(j) / q(j)+1
    #pragma unroll
    for (int j = 0; j < 12; ++j) {
        const int      m  = 64 * j + lane;
        const unsigned e0 = 4u * (unsigned)m;
        const unsigned q  = e0 / 3u;
        const unsigned q1 = q + 1u;
        const unsigned sm0 = (unsigned)__shfl((int)selmask, (int)(q  & 63u), 64);
        const unsigned sm1 = (unsigned)__shfl((int)selmask, (int)(q1 & 63u), 64);
        cb0 |= ((sm0 >> (q  >> 6)) & 1u) << j;
        cb1 |= ((sm1 >> (q1 >> 6)) & 1u) << j;
    }

    // ---- phase 4: pure 12-store burst from registers. No loads, no waits;
    // wave retires immediately after -> next block's select runs under drain.
    f32x4* dst4 = reinterpret_cast<f32x4*>(out + (size_t)bt * (NPTS * 3));
    #pragma unroll
    for (int j = 0; j < 12; ++j) {
        const int      m  = 64 * j + lane;
        const unsigned e0 = 4u * (unsigned)m;
        const unsigned q  = e0 / 3u;
        const unsigned u  = e0 - 3u * q;      // 0..2: chunk-start offset in point q
        const unsigned b0 = (cb0 >> j) & 1u;
        const unsigned b1 = (cb1 >> j) & 1u;
        f32x4 v;
        v.x = b0                    ? g[j].x : 0.0f;   // elem e0   -> point q
        v.y = ((u == 2u) ? b1 : b0) ? g[j].y : 0.0f;   // elem e0+1
        v.z = ((u == 0u) ? b0 : b1) ? g[j].z : 0.0f;   // elem e0+2
        v.w = b1                    ? g[j].w : 0.0f;   // elem e0+3 -> point q+1
        dst4[m] = v;
    }
}

extern "C" void kernel_launch(void* const* d_in, const int* in_sizes, int n_in,
                              void* d_out, int out_size, void* d_ws, size_t ws_size,
                              hipStream_t stream) {
    const float* pc  = (const float*)d_in[0];  // (B,1024,3)
    const float* tgt = (const float*)d_in[1];  // (B,21,3)
    float*       out = (float*)d_out;          // (B,21,1024,3)

    const int B        = in_sizes[0] / (NPTS * 3);   // 512
    const int total_bt = B * NT;                      // 10752
    const int nblocks  = (total_bt + 3) / 4;          // 2688 (divisible by 8)

    knn_mask_burst_kernel<<<nblocks, BLOCK, 0, stream>>>(pc, tgt, out, total_bt);
}

// Round 15
// 34.941 us; speedup vs baseline: 2.8519x; 1.1570x over previous
//
#include <hip/hip_runtime.h>

constexpr int NPTS  = 1024;   // points per batch
constexpr int NT    = 21;     // targets per batch
constexpr int KSEL  = 64;     // top-k
constexpr int BLOCK = 256;    // 4 waves, 1 wave per (b,t)
constexpr int PPL   = 16;     // points per lane (1024 / 64)
constexpr int NXCD  = 8;

typedef float f32x4 __attribute__((ext_vector_type(4)));

__device__ __forceinline__ unsigned key_of(float d) {
    // monotone float->uint transform (total order matching float <)
    unsigned u = __float_as_uint(d);
    return (u & 0x80000000u) ? ~u : (u | 0x80000000u);
}

__device__ __forceinline__ unsigned mbcnt64(unsigned long long m) {
    unsigned lo = __builtin_amdgcn_mbcnt_lo((unsigned)m, 0u);
    return __builtin_amdgcn_mbcnt_hi((unsigned)(m >> 32), lo);
}

__global__ __launch_bounds__(BLOCK) void knn_mask_fused_kernel(
    const float* __restrict__ pc,   // (B, 1024, 3)
    const float* __restrict__ tgt,  // (B, 21, 3)
    float* __restrict__ out,        // (B, 21, 1024, 3)
    int total_bt)
{
    const int wave = threadIdx.x >> 6;
    const int lane = threadIdx.x & 63;
    // bijective XCD swizzle (gridDim.x divisible by 8)
    const int cpx  = gridDim.x / NXCD;
    const int sbid = ((int)blockIdx.x % NXCD) * cpx + (int)blockIdx.x / NXCD;
    const int bt   = sbid * 4 + wave;
    if (bt >= total_bt) return;          // wave-uniform
    const int b  = bt / NT;
    const int tq = bt % NT;

    const float* base  = pc  + (size_t)b  * (NPTS * 3);
    float*       obase = out + (size_t)bt * (NPTS * 3);

    // ---- phase 0: select-independent zeroing of the whole output row.
    // Issued at t=0 so the write pipe is saturated during the select chain of
    // every co-resident wave (the only overlap scheme that survived testing).
    {
        f32x4* dst4 = reinterpret_cast<f32x4*>(obase);
        const f32x4 z = {0.0f, 0.0f, 0.0f, 0.0f};
        #pragma unroll
        for (int j = 0; j < 12; ++j) dst4[64 * j + lane] = z;
    }

    // target point (wave-uniform, L1-broadcast)
    const float* tp = tgt + ((size_t)b * NT + tq) * 3;
    const float  t0 = tp[0], t1 = tp[1], t2 = tp[2];
    const float  dt = t0 * t0 + t1 * t1 + t2 * t2;

    // ---- phase 1: strided ownership (lane owns points 64*i + lane) ----
    unsigned key[PPL];
    #pragma unroll
    for (int i = 0; i < PPL; ++i) {
        const float* pp = base + 3 * (64 * i + lane);
        const float p0 = pp[0], p1 = pp[1], p2 = pp[2];
        const float d  = dt + (p0 * p0 + p1 * p1 + p2 * p2)
                            - 2.0f * (t0 * p0 + t1 * p1 + t2 * p2);
        key[i] = key_of(d);
    }

    // ---- phase 2: threshold-form exact select of the KSEL-th smallest ----
    // wave-wide AND/OR skips all common high bits
    unsigned kand = key[0], kor = key[0];
    #pragma unroll
    for (int i = 1; i < PPL; ++i) { kand &= key[i]; kor |= key[i]; }
    #pragma unroll
    for (int off = 32; off > 0; off >>= 1) {
        kand &= (unsigned)__shfl_xor((int)kand, off, 64);
        kor  |= (unsigned)__shfl_xor((int)kor,  off, 64);
    }
    const unsigned dis = kor & ~kand;    // bits where keys disagree

    unsigned lo = 0, below = 0, want = KSEL, cls = NPTS;
    bool     early = false;
    unsigned Tsel = 0, kth = 0;
    if (dis == 0u) {
        kth = kand;                       // all 1024 keys identical
    } else {
        const int hb = 31 - __builtin_clz(dis);
        lo = (hb == 31) ? 0u : (kand & (~0u << (hb + 1)));  // common high bits
        for (int s = hb; s >= 0; --s) {
            const unsigned mid = lo | (1u << s);
            unsigned cnt = 0;
            #pragma unroll
            for (int i = 0; i < PPL; ++i) cnt += (key[i] < mid) ? 1u : 0u;
            unsigned c = 0;               // wave total via 5-ballot decompose
            #pragma unroll
            for (int j = 0; j < 5; ++j)
                c += (unsigned)__popcll(__ballot((cnt >> j) & 1u)) << j;
            const unsigned t = c - below; // size of class-0 = [lo, mid)
            if (want <= t) { cls = t; }
            else { want -= t; below = c; lo = mid; cls -= t; }
            if (cls == want) { early = true; Tsel = lo + (1u << s); break; }
        }
        if (!early) kth = lo;
    }

    // ---- phase 3: selection flags. bit i => point (64*i + lane). ----
    unsigned selmask = 0;
    if (early) {
        #pragma unroll
        for (int i = 0; i < PPL; ++i)
            if (key[i] < Tsel) selmask |= (1u << i);
    } else {
        unsigned run_tot = 0;   // stable lowest-index ties: index = 64*i + lane
        #pragma unroll
        for (int i = 0; i < PPL; ++i) {
            const bool eq = (key[i] == kth);
            const unsigned long long bal = __ballot(eq);
            const bool sel_eq = eq && (run_tot + mbcnt64(bal)) < want;
            if (key[i] < kth || sel_eq) selmask |= (1u << i);
            run_tot += (unsigned)__popcll(bal);
        }
    }

    // ---- phase 4: store ONLY the selected points (~1/lane, 12 B each).
    // vmcnt(0) orders vs the phase-0 zero stores (retired during the select
    // chain); value stores merge into still-dirty L2 lines where resident.
    asm volatile("s_waitcnt vmcnt(0)" ::: "memory");
    unsigned sm = selmask;
    while (sm) {
        const int i = __builtin_ctz(sm);
        sm &= sm - 1u;
        const int q = 64 * i + lane;
        const float* pp = base  + 3 * q;   // L1/L2-hot (read in phase 1)
        float*       op = obase + 3 * q;
        op[0] = pp[0];
        op[1] = pp[1];
        op[2] = pp[2];
    }
}

extern "C" void kernel_launch(void* const* d_in, const int* in_sizes, int n_in,
                              void* d_out, int out_size, void* d_ws, size_t ws_size,
                              hipStream_t stream) {
    const float* pc  = (const float*)d_in[0];  // (B,1024,3)
    const float* tgt = (const float*)d_in[1];  // (B,21,3)
    float*       out = (float*)d_out;          // (B,21,1024,3)

    const int B        = in_sizes[0] / (NPTS * 3);   // 512
    const int total_bt = B * NT;                      // 10752
    const int nblocks  = (total_bt + 3) / 4;          // 2688 (divisible by 8)

    knn_mask_fused_kernel<<<nblocks, BLOCK, 0, stream>>>(pc, tgt, out, total_bt);
}